// Round 15
// baseline (1689.616 us; speedup 1.0000x reference)
//
#include <hip/hip_runtime.h>
#include <hip/hip_bf16.h>
#include <math.h>

// ---------------------------------------------------------------------------
// Base = round-14 passing build (1.235 ms). Delta: conv0 restructured.
//  - cast_bf16_kernel: feature f32 -> featb bf16 (streaming, float4->short4),
//    featb parked in d_out's dead logits region (151 MB << 226 MB span;
//    consumed by conv0 before resize96 overwrites it). d_ws layout untouched.
//  - conv0_direct: ZERO-LDS, ZERO-barrier MFMA implicit GEMM (r2 structure):
//    A-fragments 16B/lane direct from featb (L1-reused across taps),
//    B-fragments wave-uniform from wf0. Four prior LDS-staged variants all
//    plateaued at ~365 us; this removes the stage/barrier serialization.
// Everything else byte-identical to round 14.
// ---------------------------------------------------------------------------

#define NLOC 64

typedef __attribute__((ext_vector_type(8))) short short8_t;
typedef __attribute__((ext_vector_type(4))) short short4_t;
typedef __attribute__((ext_vector_type(4))) float f32x4;

__device__ __forceinline__ float gelu_f(float x) {
    return 0.5f * x * (1.0f + tanhf(0.7978845608028654f * (x + 0.044715f * x * x * x)));
}

__device__ __forceinline__ short f2bf(float x) {
    union { __hip_bfloat16 h; short s; } u;
    u.h = __float2bfloat16(x);
    return u.s;
}

__device__ __forceinline__ float bf2f(short s) {
    union { unsigned u; float f; } u;
    u.u = ((unsigned)(unsigned short)s) << 16;
    return u.f;
}

// antialiased linear 12 -> 4 weight matrix (jax.image.resize, scale=1/3)
__constant__ float W12c[4][12] = {
    {0.25f, 0.375f, 0.25f, 0.125f, 0.f, 0.f, 0.f, 0.f, 0.f, 0.f, 0.f, 0.f},
    {0.f, 0.f, 1.f/9.f, 2.f/9.f, 1.f/3.f, 2.f/9.f, 1.f/9.f, 0.f, 0.f, 0.f, 0.f, 0.f},
    {0.f, 0.f, 0.f, 0.f, 0.f, 1.f/9.f, 2.f/9.f, 1.f/3.f, 2.f/9.f, 1.f/9.f, 0.f, 0.f},
    {0.f, 0.f, 0.f, 0.f, 0.f, 0.f, 0.f, 0.f, 0.125f, 0.25f, 0.375f, 0.25f}};

__device__ __forceinline__ void up_w(int i, float ratio, int inmax,
                                     int& j0, int& j1, float& w0, float& w1) {
    float c = ((float)i + 0.5f) * ratio - 0.5f;
    float fj = floorf(c);
    float f = c - fj;
    int jj = (int)fj;
    j0 = min(max(jj, 0), inmax);
    j1 = min(max(jj + 1, 0), inmax);
    w0 = 1.f - f;
    w1 = f;
}

// ---------------------------------------------------------------------------
// f32 -> bf16 streaming cast, n4 = count/4
// ---------------------------------------------------------------------------
__global__ __launch_bounds__(256) void cast_bf16_kernel(const float* __restrict__ in,
                                                        short* __restrict__ o, long n4) {
    long idx = (long)blockIdx.x * 256 + threadIdx.x;
    const long stride = (long)gridDim.x * 256;
    for (long i = idx; i < n4; i += stride) {
        const float4 v = ((const float4*)in)[i];
        short4_t s;
        s.x = f2bf(v.x);
        s.y = f2bf(v.y);
        s.z = f2bf(v.z);
        s.w = f2bf(v.w);
        ((short4_t*)o)[i] = s;
    }
}

// ---------------------------------------------------------------------------
// weight fragment packing (validated)
// wf0[tap][kk(8)][nt(3)][lane][e], ci = kk*32+8g+e, co = nt*16+(lane&15)
// ---------------------------------------------------------------------------
__global__ void prep_w0_kernel(const float* __restrict__ w0, short* __restrict__ wf) {
    const int tid = blockIdx.x * 256 + threadIdx.x;
    if (tid >= 27 * 8 * 3 * 64) return;
    const int lane = tid & 63;
    const int t2 = tid >> 6;
    const int nt = t2 % 3;
    const int t3 = t2 / 3;
    const int kk = t3 & 7, tap = t3 >> 3;
    const int g = lane >> 4, rr = lane & 15;
    const int co = nt * 16 + rr;
    short8_t frag;
#pragma unroll
    for (int e = 0; e < 8; e++) {
        const int ci = kk * 32 + g * 8 + e;
        frag[e] = f2bf(w0[((long)(tap * 256 + ci)) * 48 + co]);
    }
    ((short8_t*)wf)[tid] = frag;
}

__global__ void prep_w1_kernel(const float* __restrict__ w1, short* __restrict__ wf) {
    const int tid = blockIdx.x * 256 + threadIdx.x;
    if (tid >= 27 * 2 * 3 * 64) return;
    const int lane = tid & 63;
    const int t2 = tid >> 6;
    const int nt = t2 % 3;
    const int t3 = t2 / 3;
    const int kk = t3 & 1, tap = t3 >> 1;
    const int g = lane >> 4, rr = lane & 15;
    const int co = nt * 16 + rr;
    short8_t frag;
#pragma unroll
    for (int e = 0; e < 8; e++) {
        const int ci = kk * 32 + g * 8 + e;
        frag[e] = (ci < 48) ? f2bf(w1[((long)(tap * 48 + ci)) * 48 + co]) : (short)0;
    }
    ((short8_t*)wf)[tid] = frag;
}

// ---------------------------------------------------------------------------
// conv0_direct: no LDS, no barriers. A-fragments direct from bf16 featb
// (lane r = voxel, chunk g*8 within the 256-ch row), B from wf0.
// wave = 64 linear voxels (4 M-tiles), 3 N-tiles, K = 27 taps x 8 kk.
// bf16 output (conv1's A input).
// ---------------------------------------------------------------------------
__global__ __launch_bounds__(256) void conv0_direct(const short* __restrict__ featb,
                                                    const short* __restrict__ wf,
                                                    const float* __restrict__ bias,
                                                    short* __restrict__ x0b) {
    const int lane = threadIdx.x & 63;
    const int wid = threadIdx.x >> 6;
    const int g = lane >> 4, r = lane & 15;
    const int vbase = blockIdx.x * 256 + wid * 64;
    int vx[4], vy[4], vz[4];
#pragma unroll
    for (int mt = 0; mt < 4; mt++) {
        const int v = vbase + mt * 16 + r;
        vx[mt] = v % 96;
        vy[mt] = (v / 96) % 96;
        vz[mt] = v / 9216;
    }
    f32x4 acc[4][3];
#pragma unroll
    for (int mt = 0; mt < 4; mt++)
#pragma unroll
        for (int nt = 0; nt < 3; nt++) acc[mt][nt] = (f32x4){0.f, 0.f, 0.f, 0.f};
    const short8_t zfrag = {0, 0, 0, 0, 0, 0, 0, 0};
    const short8_t* wf8 = (const short8_t*)wf;

    for (int tap = 0; tap < 27; tap++) {
        const int dz = tap / 9 - 1, dy = (tap / 3) % 3 - 1, dxx = tap % 3 - 1;
        long aoff[4];
        bool val[4];
#pragma unroll
        for (int mt = 0; mt < 4; mt++) {
            const int zz = vz[mt] + dz, yy = vy[mt] + dy, xx = vx[mt] + dxx;
            val[mt] = ((unsigned)zz < 32u) && ((unsigned)yy < 96u) && ((unsigned)xx < 96u);
            aoff[mt] = ((((long)zz * 96 + yy) * 96 + xx) << 8) + g * 8;
        }
        const short8_t* bp = wf8 + (size_t)tap * 1536 + lane;
        for (int kk = 0; kk < 8; kk++) {
            short8_t bfr[3];
#pragma unroll
            for (int nt = 0; nt < 3; nt++) bfr[nt] = bp[kk * 192 + nt * 64];
            short8_t afr[4];
#pragma unroll
            for (int mt = 0; mt < 4; mt++)
                afr[mt] = val[mt] ? *(const short8_t*)(featb + aoff[mt] + kk * 32) : zfrag;
#pragma unroll
            for (int mt = 0; mt < 4; mt++)
#pragma unroll
                for (int nt = 0; nt < 3; nt++)
                    acc[mt][nt] = __builtin_amdgcn_mfma_f32_16x16x32_bf16(afr[mt], bfr[nt],
                                                                          acc[mt][nt], 0, 0, 0);
        }
    }
    // D mapping: col = lane&15, row = g*4 + reg (linear voxel order)
#pragma unroll
    for (int nt = 0; nt < 3; nt++) {
        const int co = nt * 16 + r;
        const float bv = bias[co];
#pragma unroll
        for (int mt = 0; mt < 4; mt++) {
            const int vox = vbase + mt * 16 + g * 4;
#pragma unroll
            for (int rg = 0; rg < 4; rg++)
                x0b[(long)(vox + rg) * 48 + co] = f2bf(gelu_f(acc[mt][nt][rg] + bv));
        }
    }
}

// ---------------------------------------------------------------------------
// conv1: bf16 in, single full-48ch halo staging, bf16 out (validated r14)
// ---------------------------------------------------------------------------
#define HV 600
#define C1ROW 48

__global__ __launch_bounds__(256, 1) void conv1_mfma_b(const short* __restrict__ x0b,
                                                       const short* __restrict__ wf,
                                                       const float* __restrict__ bias,
                                                       short* __restrict__ x1b) {
    __shared__ short slds[HV * C1ROW];
    const int tid = threadIdx.x;
    const int lane = tid & 63, wid = tid >> 6;
    const int g = lane >> 4, r = lane & 15;
    const int bz = blockIdx.x / 144, by = (blockIdx.x / 12) % 12, bx = blockIdx.x % 12;
    const int z0 = bz * 4, y0 = by * 8, x0c = bx * 8;
    int h0[4];
#pragma unroll
    for (int mt = 0; mt < 4; mt++) {
        const int t = wid * 64 + mt * 16 + r;
        h0[mt] = ((t >> 6) * 10 + ((t >> 3) & 7)) * 10 + (t & 7);
    }
    f32x4 acc[4][3];
#pragma unroll
    for (int mt = 0; mt < 4; mt++)
#pragma unroll
        for (int nt = 0; nt < 3; nt++) acc[mt][nt] = (f32x4){0.f, 0.f, 0.f, 0.f};
    const short8_t zfrag = {0, 0, 0, 0, 0, 0, 0, 0};
    const short8_t* wf8 = (const short8_t*)wf;

    for (int h = tid; h < HV; h += 256) {
        const int hx = h % 10, hy = (h / 10) % 10, hz = h / 100;
        const int zz = z0 + hz - 1, yy = y0 + hy - 1, xx = x0c + hx - 1;
        short8_t s8[6];
        if ((unsigned)zz < 32u && (unsigned)yy < 96u && (unsigned)xx < 96u) {
            const short8_t* src = (const short8_t*)(x0b + (((long)zz * 96 + yy) * 96 + xx) * 48);
#pragma unroll
            for (int q = 0; q < 6; q++) s8[q] = src[q];
        } else {
#pragma unroll
            for (int q = 0; q < 6; q++) s8[q] = zfrag;
        }
        short8_t* dst = (short8_t*)(slds + h * C1ROW);
#pragma unroll
        for (int q = 0; q < 6; q++) dst[q] = s8[q];
    }
    __syncthreads();

    for (int tap = 0; tap < 27; tap++) {
        const int dh = (tap / 9) * 100 + ((tap / 3) % 3) * 10 + (tap % 3);
#pragma unroll
        for (int kk = 0; kk < 2; kk++) {
            short8_t bfr[3];
#pragma unroll
            for (int nt = 0; nt < 3; nt++)
                bfr[nt] = wf8[(size_t)tap * 384 + kk * 192 + nt * 64 + lane];
            short8_t afr[4];
#pragma unroll
            for (int mt = 0; mt < 4; mt++) {
                afr[mt] = zfrag;
                if (!(kk == 1 && g >= 2))  // ci = kk*32+8g < 48
                    afr[mt] =
                        *(const short8_t*)(slds + (h0[mt] + dh) * C1ROW + kk * 32 + g * 8);
            }
#pragma unroll
            for (int mt = 0; mt < 4; mt++)
#pragma unroll
                for (int nt = 0; nt < 3; nt++)
                    acc[mt][nt] = __builtin_amdgcn_mfma_f32_16x16x32_bf16(afr[mt], bfr[nt],
                                                                          acc[mt][nt], 0, 0, 0);
        }
    }
#pragma unroll
    for (int nt = 0; nt < 3; nt++) {
        const int co = nt * 16 + r;
        const float bv = bias[co];
#pragma unroll
        for (int mt = 0; mt < 4; mt++) {
#pragma unroll
            for (int rg = 0; rg < 4; rg++) {
                const int t = wid * 64 + mt * 16 + g * 4 + rg;
                const int z = z0 + (t >> 6), y = y0 + ((t >> 3) & 7), x = x0c + (t & 7);
                const long gi = ((long)z * 96 + y) * 96 + x;
                x1b[gi * 48 + co] = f2bf(acc[mt][nt][rg] + bv);
            }
        }
    }
}

// ---------------------------------------------------------------------------
// per-patch channel partial sums per z-slice (bf16 x1); part[n][i][48]
// ---------------------------------------------------------------------------
__global__ __launch_bounds__(256) void mean_part_kernel(const short* __restrict__ x1b,
                                                        const float* __restrict__ locations,
                                                        float* __restrict__ part) {
    __shared__ float red[256];
    const int n = blockIdx.x, i = blockIdx.y;
    const int tid = threadIdx.x;
    const int ch = tid & 63, grp = tid >> 6;
    const int lz = (int)(locations[n * 3 + 0] * 0.25f) - 12;
    const int ly = (int)(locations[n * 3 + 1] * 0.25f) - 12;
    const int lx = (int)(locations[n * 3 + 2] * 0.25f) - 12;
    float acc = 0.f;
    const int z = lz + i;
    if (ch < 48 && (unsigned)z < 32u) {
        for (int p = grp; p < 576; p += 4) {
            const int j = p / 24, k = p % 24;
            const int y = ly + j, x = lx + k;
            if ((unsigned)y < 96u && (unsigned)x < 96u)
                acc += bf2f(x1b[(((long)z * 96 + y) * 96 + x) * 48 + ch]);
        }
    }
    red[tid] = acc;
    __syncthreads();
    if (tid < 48)
        part[(n * 24 + i) * 48 + tid] = red[tid] + red[tid + 64] + red[tid + 128] + red[tid + 192];
}

__global__ void gate_kernel(const float* __restrict__ part, const float* __restrict__ caw,
                            const float* __restrict__ cab, float* __restrict__ gate) {
    __shared__ float sm[48];
    const int n = blockIdx.x, t = threadIdx.x;
    if (t < 48) {
        float a = 0.f;
        for (int i = 0; i < 24; i++) a += part[(n * 24 + i) * 48 + t];
        sm[t] = a * (1.f / 13824.f);
    }
    __syncthreads();
    if (t < 48) {
        float g = cab[t];
        for (int c = 0; c < 48; c++) g += sm[c] * caw[c * 48 + t];
        gate[n * 48 + t] = 1.f / (1.f + expf(-g));
    }
}

// ---------------------------------------------------------------------------
// separable antialiased 12^3 -> 4^3 resize (bf16 x1 input)
// ---------------------------------------------------------------------------
__global__ __launch_bounds__(256) void rs1_kernel(const short* __restrict__ x1b,
                                                  const float* __restrict__ locations,
                                                  const float* __restrict__ gate,
                                                  float* __restrict__ t1) {
    const int idx = blockIdx.x * 256 + threadIdx.x;
    int ch = idx % 48;
    int r = idx / 48;
    int c4 = r & 3; r >>= 2;
    int j = r % 12; r /= 12;
    int i = r % 12;
    int n = r / 12;
    const int lz = (int)(locations[n * 3 + 0] * 0.25f) - 6;
    const int ly = (int)(locations[n * 3 + 1] * 0.25f) - 6;
    const int lx = (int)(locations[n * 3 + 2] * 0.25f) - 6;
    const int z = lz + i, y = ly + j;
    float acc = 0.f;
    if ((unsigned)z < 32u && (unsigned)y < 96u) {
        const short* row = x1b + (((long)z * 96 + y) * 96) * 48 + ch;
#pragma unroll
        for (int k = 0; k < 12; k++) {
            const int x = lx + k;
            if ((unsigned)x < 96u) acc += W12c[c4][k] * bf2f(row[(long)x * 48]);
        }
    }
    t1[idx] = acc * gate[n * 48 + ch];
}

__global__ __launch_bounds__(256) void rs2_kernel(const float* __restrict__ t1,
                                                  float* __restrict__ t2) {
    const int idx = blockIdx.x * 256 + threadIdx.x;
    int ch = idx % 48;
    int r = idx / 48;
    int c = r & 3; r >>= 2;
    int b = r & 3; r >>= 2;
    int i = r % 12;
    int n = r / 12;
    float acc = 0.f;
#pragma unroll
    for (int j = 0; j < 12; j++)
        acc += W12c[b][j] * t1[(((long)((n * 12 + i) * 12 + j) * 4 + c)) * 48 + ch];
    t2[idx] = acc;
}

__global__ __launch_bounds__(256) void rs3_kernel(const float* __restrict__ t2,
                                                  float* __restrict__ rs) {
    const int idx = blockIdx.x * 256 + threadIdx.x;
    int ch = idx % 48;
    int r = idx / 48;
    int c = r & 3; r >>= 2;
    int b = r & 3; r >>= 2;
    int a = r & 3;
    int n = r >> 2;
    float acc = 0.f;
#pragma unroll
    for (int i = 0; i < 12; i++)
        acc += W12c[a][i] * t2[(((long)((n * 12 + i) * 4 + b) * 4 + c)) * 48 + ch];
    rs[idx] = acc;
}

// ---------------------------------------------------------------------------
// small dense layers (known good)
// ---------------------------------------------------------------------------
template <int K, bool GEL>
__global__ __launch_bounds__(256) void mlp_kernel(const float* __restrict__ A,
                                                  const float* __restrict__ W,
                                                  const float* __restrict__ bias,
                                                  float* __restrict__ C, int N) {
    const int n = threadIdx.x & 63;
    const int j = blockIdx.x * 4 + (threadIdx.x >> 6);
    float acc = bias[j];
    const float* a = A + (long)n * K;
    const float* wp = W + j;
    for (int k = 0; k < K; k++) acc += a[k] * wp[(long)k * N];
    if (GEL) acc = gelu_f(acc);
    C[(long)n * N + j] = acc;
}

// LayerNorm over 1024 (known good); writes patch_sigs (output 0)
__global__ __launch_bounds__(256) void ln_kernel(const float* __restrict__ s,
                                                 const float* __restrict__ sc,
                                                 const float* __restrict__ bi,
                                                 float* __restrict__ out) {
    __shared__ float red[256];
    const int n = blockIdx.x, tid = threadIdx.x;
    float4 v = ((const float4*)(s + (long)n * 1024))[tid];
    red[tid] = v.x + v.y + v.z + v.w;
    __syncthreads();
    for (int off = 128; off > 0; off >>= 1) {
        if (tid < off) red[tid] += red[tid + off];
        __syncthreads();
    }
    const float mu = red[0] * (1.f / 1024.f);
    __syncthreads();
    const float d0 = v.x - mu, d1 = v.y - mu, d2 = v.z - mu, d3 = v.w - mu;
    red[tid] = d0 * d0 + d1 * d1 + d2 * d2 + d3 * d3;
    __syncthreads();
    for (int off = 128; off > 0; off >>= 1) {
        if (tid < off) red[tid] += red[tid + off];
        __syncthreads();
    }
    const float rstd = rsqrtf(red[0] * (1.f / 1024.f) + 1e-6f);
    const int base = n * 1024 + tid * 4;
    out[base + 0] = d0 * rstd * sc[tid * 4 + 0] + bi[tid * 4 + 0];
    out[base + 1] = d1 * rstd * sc[tid * 4 + 1] + bi[tid * 4 + 1];
    out[base + 2] = d2 * rstd * sc[tid * 4 + 2] + bi[tid * 4 + 2];
    out[base + 3] = d3 * rstd * sc[tid * 4 + 3] + bi[tid * 4 + 3];
}

// ---------------------------------------------------------------------------
// fused pos-enc resize + proj + relu + conv_transpose (bf16 x1 input)
// ---------------------------------------------------------------------------
__global__ __launch_bounds__(256) void deconv_kernel(const short* __restrict__ x1b,
                                                     const float* __restrict__ locations,
                                                     const float* __restrict__ gate,
                                                     const float* __restrict__ p3,
                                                     const float* __restrict__ projw,
                                                     const float* __restrict__ ctw,
                                                     const float* __restrict__ ctb,
                                                     float* __restrict__ l48) {
    __shared__ float s_ctw[384], s_proj[192], s_gate[48];
    const int n = blockIdx.y, tid = threadIdx.x;
    for (int i = tid; i < 384; i += 256) s_ctw[i] = ctw[i];
    if (tid < 192) s_proj[tid] = projw[tid];
    if (tid < 48) s_gate[tid] = gate[n * 48 + tid];
    __syncthreads();
    const int vox = blockIdx.x * 256 + tid;
    const int q = vox % 24, pp = (vox / 24) % 24, m = vox / 576;
    const int lz = (int)(locations[n * 3 + 0] * 0.25f) - 12;
    const int ly = (int)(locations[n * 3 + 1] * 0.25f) - 12;
    const int lx = (int)(locations[n * 3 + 2] * 0.25f) - 12;
    const int z = lz + m, y = ly + pp, x = lx + q;
    float pf[48];
    const bool valid = (unsigned)z < 32u && (unsigned)y < 96u && (unsigned)x < 96u;
    if (valid) {
        const short8_t* src = (const short8_t*)(x1b + (((long)z * 96 + y) * 96 + x) * 48);
#pragma unroll
        for (int t8 = 0; t8 < 6; t8++) {
            const short8_t v = src[t8];
#pragma unroll
            for (int e = 0; e < 8; e++) pf[t8 * 8 + e] = bf2f(v[e]) * s_gate[t8 * 8 + e];
        }
    } else {
#pragma unroll
        for (int c = 0; c < 48; c++) pf[c] = 0.f;
    }
    int jz[2], jy[2], jx[2];
    float wz[2], wy[2], wx[2];
    const float r3 = 1.f / 3.f;
    up_w(m, r3, 7, jz[0], jz[1], wz[0], wz[1]);
    up_w(pp, r3, 7, jy[0], jy[1], wy[0], wy[1]);
    up_w(q, r3, 7, jx[0], jx[1], wx[0], wx[1]);
    const float4* prow = (const float4*)(p3 + (long)n * 2048);
    float prx = 0.f, pry = 0.f, prz = 0.f, prw = 0.f;
#pragma unroll
    for (int a = 0; a < 2; a++)
#pragma unroll
        for (int b = 0; b < 2; b++)
#pragma unroll
            for (int c = 0; c < 2; c++) {
                const float wgt = wz[a] * wy[b] * wx[c];
                float4 v = prow[(jz[a] * 8 + jy[b]) * 8 + jx[c]];
                prx += wgt * v.x;
                pry += wgt * v.y;
                prz += wgt * v.z;
                prw += wgt * v.w;
            }
#pragma unroll
    for (int c = 0; c < 48; c++) {
        float v = pf[c] + prx * s_proj[c] + pry * s_proj[48 + c] + prz * s_proj[96 + c] +
                  prw * s_proj[144 + c];
        pf[c] = fmaxf(v, 0.f);
    }
    const float bias = ctb[0];
#pragma unroll
    for (int a = 0; a < 2; a++)
#pragma unroll
        for (int b = 0; b < 2; b++)
#pragma unroll
            for (int c = 0; c < 2; c++) {
                const float* wrow = s_ctw + (((1 - a) * 2 + (1 - b)) * 2 + (1 - c)) * 48;
                float acc = bias;
#pragma unroll
                for (int ch = 0; ch < 48; ch++) acc += pf[ch] * wrow[ch];
                l48[(((long)n * 48 + 2 * m + a) * 48 + 2 * pp + b) * 48 + 2 * q + c] = acc;
            }
}

// final linear x2 upsample 48^3 -> 96^3 (known good)
__global__ __launch_bounds__(256) void resize96_kernel(const float* __restrict__ l48,
                                                       float* __restrict__ out) {
    const int n = blockIdx.y;
    const int vox = blockIdx.x * 256 + threadIdx.x;
    const int kx = vox % 96, jy = (vox / 96) % 96, iz = vox / 9216;
    int a0, a1, b0, b1, c0, c1;
    float wa0, wa1, wb0, wb1, wc0, wc1;
    up_w(iz, 0.5f, 47, a0, a1, wa0, wa1);
    up_w(jy, 0.5f, 47, b0, b1, wb0, wb1);
    up_w(kx, 0.5f, 47, c0, c1, wc0, wc1);
    const float* base = l48 + (long)n * 110592;
    const float v =
        wa0 * (wb0 * (wc0 * base[(a0 * 48 + b0) * 48 + c0] + wc1 * base[(a0 * 48 + b0) * 48 + c1]) +
               wb1 * (wc0 * base[(a0 * 48 + b1) * 48 + c0] + wc1 * base[(a0 * 48 + b1) * 48 + c1])) +
        wa1 * (wb0 * (wc0 * base[(a1 * 48 + b0) * 48 + c0] + wc1 * base[(a1 * 48 + b0) * 48 + c1]) +
               wb1 * (wc0 * base[(a1 * 48 + b1) * 48 + c0] + wc1 * base[(a1 * 48 + b1) * 48 + c1]));
    out[(long)n * 884736 + vox] = v;
}

__global__ void tail_kernel(const float* __restrict__ locations, float* __restrict__ out) {
    const int n = threadIdx.x;
    if (n < NLOC) {
        const float l0 = locations[n * 3 + 0] * 0.25f;
        const float l1 = locations[n * 3 + 1] * 0.25f;
        const float l2 = locations[n * 3 + 2] * 0.25f;
        const int z = (int)l0 - 12, y = (int)l1 - 12, x = (int)l2 - 12;
        const bool mask = (l2 >= 0.f);
        out[n] = mask ? (float)(z * 4) : -1.f;
        out[64 + n] = mask ? (float)(y * 4) : -1.f;
        out[128 + n] = mask ? (float)(x * 4) : -1.f;
        out[192 + n] = mask ? 1.f : 0.f;
    }
}

// ---------------------------------------------------------------------------
// workspace layout (d_ws unchanged; peak 113.2 MB envelope).
// featb (bf16 feature copy, 151 MB) lives in d_out's dead logits region:
//   wf1   at out[65,536 .. 107,008)
//   featb at out[200,000 .. 19,074,368)   (consumed by conv0 -> dead before
//                                          resize96 rewrites [65536, 56.7M))
// ---------------------------------------------------------------------------
static const size_t OFF_X0 = 0;                 // bf16 x0b: 7,077,888 floats
static const size_t OFF_X1 = 14155776;          // bf16 x1b
static const size_t OFF_WF0 = 14155776 + 7077888;  // after x1b region start? NO:
// wf0 must not collide with x1b (x1b is bf16 = 3,538,944 floats at OFF_X1).
// Place wf0 after x1b: 14,155,776 + 3,538,944 = 17,694,720 (+165,888 -> 17,860,608 < 28,311,552)
static const size_t OFF_WF0R = 17694720;
static const size_t OFF_GATE = 4096;            // dead-x0b reuse
static const size_t OFF_T1 = 8192;
static const size_t OFF_T2 = 1777664;
static const size_t OFF_RS = 2367488;
static const size_t OFF_S = 2564096;
static const size_t OFF_P1 = 2629632;
static const size_t OFF_P2 = 2695168;
static const size_t OFF_P3 = 2760704;
static const size_t OFF_L48 = 2891776;          // ends 9,969,664
static const size_t OFF_PART = 10000000;        // -> 10,073,728 < 14,155,776

// d_out offsets (floats)
static const size_t OUT_WF1 = 65536;            // 41,472 floats (ends 107,008)
static const size_t OUT_FEATB = 200000;         // 18,874,368 floats (ends 19,074,368)

extern "C" void kernel_launch(void* const* d_in, const int* in_sizes, int n_in,
                              void* d_out, int out_size, void* d_ws, size_t ws_size,
                              hipStream_t stream) {
    const float* feature = (const float*)d_in[0];
    const float* locations = (const float*)d_in[1];
    const float* w0 = (const float*)d_in[2];
    const float* b0 = (const float*)d_in[3];
    const float* w1 = (const float*)d_in[4];
    const float* b1 = (const float*)d_in[5];
    const float* caw = (const float*)d_in[6];
    const float* cab = (const float*)d_in[7];
    const float* sigw = (const float*)d_in[8];
    const float* sigb = (const float*)d_in[9];
    const float* lnsc = (const float*)d_in[10];
    const float* lnbi = (const float*)d_in[11];
    const float* pe1w = (const float*)d_in[12];
    const float* pe1b = (const float*)d_in[13];
    const float* pe2w = (const float*)d_in[14];
    const float* pe2b = (const float*)d_in[15];
    const float* pe3w = (const float*)d_in[16];
    const float* pe3b = (const float*)d_in[17];
    const float* projw = (const float*)d_in[18];
    const float* ctw = (const float*)d_in[19];
    const float* ctb = (const float*)d_in[20];
    float* ws = (float*)d_ws;
    float* out = (float*)d_out;

    short* x0b = (short*)(ws + OFF_X0);
    short* x1b = (short*)(ws + OFF_X1);
    short* wf0 = (short*)(ws + OFF_WF0R);
    short* wf1 = (short*)(out + OUT_WF1);
    short* featb = (short*)(out + OUT_FEATB);

    // bf16 staging + weight packing
    cast_bf16_kernel<<<4096, 256, 0, stream>>>(feature, featb, 75497472L / 4);
    prep_w0_kernel<<<162, 256, 0, stream>>>(w0, wf0);
    prep_w1_kernel<<<41, 256, 0, stream>>>(w1, wf1);

    // MFMA convs: conv0 direct-global (no LDS/barriers), conv1 LDS-staged
    conv0_direct<<<1152, 256, 0, stream>>>(featb, wf0, b0, x0b);
    conv1_mfma_b<<<1152, 256, 0, stream>>>(x0b, wf1, b1, x1b);

    // gate — per-z-slice partials
    mean_part_kernel<<<dim3(64, 24), 256, 0, stream>>>(x1b, locations, ws + OFF_PART);
    gate_kernel<<<64, 64, 0, stream>>>(ws + OFF_PART, caw, cab, ws + OFF_GATE);

    // inner 12^3 -> 4^3 separable resize
    rs1_kernel<<<6912, 256, 0, stream>>>(x1b, locations, ws + OFF_GATE, ws + OFF_T1);
    rs2_kernel<<<2304, 256, 0, stream>>>(ws + OFF_T1, ws + OFF_T2);
    rs3_kernel<<<768, 256, 0, stream>>>(ws + OFF_T2, ws + OFF_RS);

    // sig GEMM + LayerNorm -> patch_sigs
    mlp_kernel<3072, false><<<256, 256, 0, stream>>>(ws + OFF_RS, sigw, sigb, ws + OFF_S, 1024);
    ln_kernel<<<64, 256, 0, stream>>>(ws + OFF_S, lnsc, lnbi, out);

    // pos-enc MLP
    mlp_kernel<1024, true><<<256, 256, 0, stream>>>(out, pe1w, pe1b, ws + OFF_P1, 1024);
    mlp_kernel<1024, true><<<256, 256, 0, stream>>>(ws + OFF_P1, pe2w, pe2b, ws + OFF_P2, 1024);
    mlp_kernel<1024, false><<<512, 256, 0, stream>>>(ws + OFF_P2, pe3w, pe3b, ws + OFF_P3, 2048);

    // fused pos-enc resize + proj + relu + conv_transpose
    deconv_kernel<<<dim3(54, 64), 256, 0, stream>>>(x1b, locations, ws + OFF_GATE, ws + OFF_P3,
                                                    projw, ctw, ctb, ws + OFF_L48);

    // final x2 upsample -> logits (overwrites wf1 + featb scratch)
    resize96_kernel<<<dim3(3456, 64), 256, 0, stream>>>(ws + OFF_L48, out + 65536);

    // plocs + mask
    tail_kernel<<<1, 64, 0, stream>>>(locations, out + 56688640);
}

// Round 16
// 1235.239 us; speedup vs baseline: 1.3678x; 1.3678x over previous
//
#include <hip/hip_runtime.h>
#include <hip/hip_bf16.h>
#include <math.h>

// ---------------------------------------------------------------------------
// REVERT to round-14 passing build (1.235 ms, best known).
// conv0_direct (r15) regressed 365->664 us: 2.07 GB FETCH, L1 cannot hold
// tap-reuse without LDS staging. LDS-staged conv0 (r11/r14) is the measured
// best of five structural variants. This file is byte-identical to r14.
// ---------------------------------------------------------------------------

#define NLOC 64

typedef __attribute__((ext_vector_type(8))) short short8_t;
typedef __attribute__((ext_vector_type(4))) float f32x4;

__device__ __forceinline__ float gelu_f(float x) {
    return 0.5f * x * (1.0f + tanhf(0.7978845608028654f * (x + 0.044715f * x * x * x)));
}

__device__ __forceinline__ short f2bf(float x) {
    union { __hip_bfloat16 h; short s; } u;
    u.h = __float2bfloat16(x);
    return u.s;
}

__device__ __forceinline__ float bf2f(short s) {
    union { unsigned u; float f; } u;
    u.u = ((unsigned)(unsigned short)s) << 16;
    return u.f;
}

// antialiased linear 12 -> 4 weight matrix (jax.image.resize, scale=1/3)
__constant__ float W12c[4][12] = {
    {0.25f, 0.375f, 0.25f, 0.125f, 0.f, 0.f, 0.f, 0.f, 0.f, 0.f, 0.f, 0.f},
    {0.f, 0.f, 1.f/9.f, 2.f/9.f, 1.f/3.f, 2.f/9.f, 1.f/9.f, 0.f, 0.f, 0.f, 0.f, 0.f},
    {0.f, 0.f, 0.f, 0.f, 0.f, 1.f/9.f, 2.f/9.f, 1.f/3.f, 2.f/9.f, 1.f/9.f, 0.f, 0.f},
    {0.f, 0.f, 0.f, 0.f, 0.f, 0.f, 0.f, 0.f, 0.125f, 0.25f, 0.375f, 0.25f}};

__device__ __forceinline__ void up_w(int i, float ratio, int inmax,
                                     int& j0, int& j1, float& w0, float& w1) {
    float c = ((float)i + 0.5f) * ratio - 0.5f;
    float fj = floorf(c);
    float f = c - fj;
    int jj = (int)fj;
    j0 = min(max(jj, 0), inmax);
    j1 = min(max(jj + 1, 0), inmax);
    w0 = 1.f - f;
    w1 = f;
}

// ---------------------------------------------------------------------------
// weight fragment packing (validated)
// ---------------------------------------------------------------------------
__global__ void prep_w0_kernel(const float* __restrict__ w0, short* __restrict__ wf) {
    const int tid = blockIdx.x * 256 + threadIdx.x;
    if (tid >= 27 * 8 * 3 * 64) return;
    const int lane = tid & 63;
    const int t2 = tid >> 6;
    const int nt = t2 % 3;
    const int t3 = t2 / 3;
    const int kk = t3 & 7, tap = t3 >> 3;
    const int g = lane >> 4, rr = lane & 15;
    const int co = nt * 16 + rr;
    short8_t frag;
#pragma unroll
    for (int e = 0; e < 8; e++) {
        const int ci = kk * 32 + g * 8 + e;
        frag[e] = f2bf(w0[((long)(tap * 256 + ci)) * 48 + co]);
    }
    ((short8_t*)wf)[tid] = frag;
}

__global__ void prep_w1_kernel(const float* __restrict__ w1, short* __restrict__ wf) {
    const int tid = blockIdx.x * 256 + threadIdx.x;
    if (tid >= 27 * 2 * 3 * 64) return;
    const int lane = tid & 63;
    const int t2 = tid >> 6;
    const int nt = t2 % 3;
    const int t3 = t2 / 3;
    const int kk = t3 & 1, tap = t3 >> 1;
    const int g = lane >> 4, rr = lane & 15;
    const int co = nt * 16 + rr;
    short8_t frag;
#pragma unroll
    for (int e = 0; e < 8; e++) {
        const int ci = kk * 32 + g * 8 + e;
        frag[e] = (ci < 48) ? f2bf(w1[((long)(tap * 48 + ci)) * 48 + co]) : (short)0;
    }
    ((short8_t*)wf)[tid] = frag;
}

// ---------------------------------------------------------------------------
// conv0: fused cast + LDS halo staging + MFMA; bf16 output (r11 exact)
// ---------------------------------------------------------------------------
#define HV 600
#define HSTR 40  // shorts per halo row (32 + 8 pad)

__global__ __launch_bounds__(256) void conv0_mfma(const float* __restrict__ feat,
                                                  const short* __restrict__ wf,
                                                  const float* __restrict__ bias,
                                                  short* __restrict__ x0b) {
    __shared__ short slds[HV * HSTR];
    const int tid = threadIdx.x;
    const int lane = tid & 63, wid = tid >> 6;
    const int g = lane >> 4, r = lane & 15;
    const int bz = blockIdx.x / 144, by = (blockIdx.x / 12) % 12, bx = blockIdx.x % 12;
    const int z0 = bz * 4, y0 = by * 8, x0c = bx * 8;
    int h0[4];
#pragma unroll
    for (int mt = 0; mt < 4; mt++) {
        const int t = wid * 64 + mt * 16 + r;
        h0[mt] = ((t >> 6) * 10 + ((t >> 3) & 7)) * 10 + (t & 7);
    }
    f32x4 acc[4][3];
#pragma unroll
    for (int mt = 0; mt < 4; mt++)
#pragma unroll
        for (int nt = 0; nt < 3; nt++) acc[mt][nt] = (f32x4){0.f, 0.f, 0.f, 0.f};
    const short8_t zfrag = {0, 0, 0, 0, 0, 0, 0, 0};
    const short8_t* wf8 = (const short8_t*)wf;

    for (int kk = 0; kk < 8; kk++) {
        __syncthreads();
        for (int h = tid; h < HV; h += 256) {
            const int hx = h % 10, hy = (h / 10) % 10, hz = h / 100;
            const int zz = z0 + hz - 1, yy = y0 + hy - 1, xx = x0c + hx - 1;
            short8_t s8[4];
            if ((unsigned)zz < 32u && (unsigned)yy < 96u && (unsigned)xx < 96u) {
                const float4* src =
                    (const float4*)(feat + (((((long)zz * 96 + yy) * 96 + xx)) << 8) + kk * 32);
#pragma unroll
                for (int q = 0; q < 4; q++) {
                    const float4 a = src[2 * q], b = src[2 * q + 1];
                    s8[q][0] = f2bf(a.x); s8[q][1] = f2bf(a.y);
                    s8[q][2] = f2bf(a.z); s8[q][3] = f2bf(a.w);
                    s8[q][4] = f2bf(b.x); s8[q][5] = f2bf(b.y);
                    s8[q][6] = f2bf(b.z); s8[q][7] = f2bf(b.w);
                }
            } else {
#pragma unroll
                for (int q = 0; q < 4; q++) s8[q] = zfrag;
            }
            short8_t* dst = (short8_t*)(slds + h * HSTR);
#pragma unroll
            for (int q = 0; q < 4; q++) dst[q] = s8[q];
        }
        __syncthreads();
        for (int tap = 0; tap < 27; tap++) {
            const int dh = (tap / 9) * 100 + ((tap / 3) % 3) * 10 + (tap % 3);
            short8_t bfr[3];
#pragma unroll
            for (int nt = 0; nt < 3; nt++)
                bfr[nt] = wf8[(size_t)tap * 1536 + kk * 192 + nt * 64 + lane];
            short8_t afr[4];
#pragma unroll
            for (int mt = 0; mt < 4; mt++)
                afr[mt] = *(const short8_t*)(slds + (h0[mt] + dh) * HSTR + g * 8);
#pragma unroll
            for (int mt = 0; mt < 4; mt++)
#pragma unroll
                for (int nt = 0; nt < 3; nt++)
                    acc[mt][nt] = __builtin_amdgcn_mfma_f32_16x16x32_bf16(afr[mt], bfr[nt],
                                                                          acc[mt][nt], 0, 0, 0);
        }
    }
    // D mapping: col = lane&15, row = g*4 + reg. bf16 output.
#pragma unroll
    for (int nt = 0; nt < 3; nt++) {
        const int co = nt * 16 + r;
        const float bv = bias[co];
#pragma unroll
        for (int mt = 0; mt < 4; mt++) {
#pragma unroll
            for (int rg = 0; rg < 4; rg++) {
                const int t = wid * 64 + mt * 16 + g * 4 + rg;
                const int z = z0 + (t >> 6), y = y0 + ((t >> 3) & 7), x = x0c + (t & 7);
                const long gi = ((long)z * 96 + y) * 96 + x;
                x0b[gi * 48 + co] = f2bf(gelu_f(acc[mt][nt][rg] + bv));
            }
        }
    }
}

// ---------------------------------------------------------------------------
// conv1: bf16 in, single full-48ch halo staging, bf16 out (validated r14)
// ---------------------------------------------------------------------------
#define C1ROW 48

__global__ __launch_bounds__(256, 1) void conv1_mfma_b(const short* __restrict__ x0b,
                                                       const short* __restrict__ wf,
                                                       const float* __restrict__ bias,
                                                       short* __restrict__ x1b) {
    __shared__ short slds[HV * C1ROW];
    const int tid = threadIdx.x;
    const int lane = tid & 63, wid = tid >> 6;
    const int g = lane >> 4, r = lane & 15;
    const int bz = blockIdx.x / 144, by = (blockIdx.x / 12) % 12, bx = blockIdx.x % 12;
    const int z0 = bz * 4, y0 = by * 8, x0c = bx * 8;
    int h0[4];
#pragma unroll
    for (int mt = 0; mt < 4; mt++) {
        const int t = wid * 64 + mt * 16 + r;
        h0[mt] = ((t >> 6) * 10 + ((t >> 3) & 7)) * 10 + (t & 7);
    }
    f32x4 acc[4][3];
#pragma unroll
    for (int mt = 0; mt < 4; mt++)
#pragma unroll
        for (int nt = 0; nt < 3; nt++) acc[mt][nt] = (f32x4){0.f, 0.f, 0.f, 0.f};
    const short8_t zfrag = {0, 0, 0, 0, 0, 0, 0, 0};
    const short8_t* wf8 = (const short8_t*)wf;

    for (int h = tid; h < HV; h += 256) {
        const int hx = h % 10, hy = (h / 10) % 10, hz = h / 100;
        const int zz = z0 + hz - 1, yy = y0 + hy - 1, xx = x0c + hx - 1;
        short8_t s8[6];
        if ((unsigned)zz < 32u && (unsigned)yy < 96u && (unsigned)xx < 96u) {
            const short8_t* src = (const short8_t*)(x0b + (((long)zz * 96 + yy) * 96 + xx) * 48);
#pragma unroll
            for (int q = 0; q < 6; q++) s8[q] = src[q];
        } else {
#pragma unroll
            for (int q = 0; q < 6; q++) s8[q] = zfrag;
        }
        short8_t* dst = (short8_t*)(slds + h * C1ROW);
#pragma unroll
        for (int q = 0; q < 6; q++) dst[q] = s8[q];
    }
    __syncthreads();

    for (int tap = 0; tap < 27; tap++) {
        const int dh = (tap / 9) * 100 + ((tap / 3) % 3) * 10 + (tap % 3);
#pragma unroll
        for (int kk = 0; kk < 2; kk++) {
            short8_t bfr[3];
#pragma unroll
            for (int nt = 0; nt < 3; nt++)
                bfr[nt] = wf8[(size_t)tap * 384 + kk * 192 + nt * 64 + lane];
            short8_t afr[4];
#pragma unroll
            for (int mt = 0; mt < 4; mt++) {
                afr[mt] = zfrag;
                if (!(kk == 1 && g >= 2))  // ci = kk*32+8g < 48
                    afr[mt] =
                        *(const short8_t*)(slds + (h0[mt] + dh) * C1ROW + kk * 32 + g * 8);
            }
#pragma unroll
            for (int mt = 0; mt < 4; mt++)
#pragma unroll
                for (int nt = 0; nt < 3; nt++)
                    acc[mt][nt] = __builtin_amdgcn_mfma_f32_16x16x32_bf16(afr[mt], bfr[nt],
                                                                          acc[mt][nt], 0, 0, 0);
        }
    }
#pragma unroll
    for (int nt = 0; nt < 3; nt++) {
        const int co = nt * 16 + r;
        const float bv = bias[co];
#pragma unroll
        for (int mt = 0; mt < 4; mt++) {
#pragma unroll
            for (int rg = 0; rg < 4; rg++) {
                const int t = wid * 64 + mt * 16 + g * 4 + rg;
                const int z = z0 + (t >> 6), y = y0 + ((t >> 3) & 7), x = x0c + (t & 7);
                const long gi = ((long)z * 96 + y) * 96 + x;
                x1b[gi * 48 + co] = f2bf(acc[mt][nt][rg] + bv);
            }
        }
    }
}

// ---------------------------------------------------------------------------
// per-patch channel partial sums per z-slice (bf16 x1); part[n][i][48]
// ---------------------------------------------------------------------------
__global__ __launch_bounds__(256) void mean_part_kernel(const short* __restrict__ x1b,
                                                        const float* __restrict__ locations,
                                                        float* __restrict__ part) {
    __shared__ float red[256];
    const int n = blockIdx.x, i = blockIdx.y;
    const int tid = threadIdx.x;
    const int ch = tid & 63, grp = tid >> 6;
    const int lz = (int)(locations[n * 3 + 0] * 0.25f) - 12;
    const int ly = (int)(locations[n * 3 + 1] * 0.25f) - 12;
    const int lx = (int)(locations[n * 3 + 2] * 0.25f) - 12;
    float acc = 0.f;
    const int z = lz + i;
    if (ch < 48 && (unsigned)z < 32u) {
        for (int p = grp; p < 576; p += 4) {
            const int j = p / 24, k = p % 24;
            const int y = ly + j, x = lx + k;
            if ((unsigned)y < 96u && (unsigned)x < 96u)
                acc += bf2f(x1b[(((long)z * 96 + y) * 96 + x) * 48 + ch]);
        }
    }
    red[tid] = acc;
    __syncthreads();
    if (tid < 48)
        part[(n * 24 + i) * 48 + tid] = red[tid] + red[tid + 64] + red[tid + 128] + red[tid + 192];
}

__global__ void gate_kernel(const float* __restrict__ part, const float* __restrict__ caw,
                            const float* __restrict__ cab, float* __restrict__ gate) {
    __shared__ float sm[48];
    const int n = blockIdx.x, t = threadIdx.x;
    if (t < 48) {
        float a = 0.f;
        for (int i = 0; i < 24; i++) a += part[(n * 24 + i) * 48 + t];
        sm[t] = a * (1.f / 13824.f);
    }
    __syncthreads();
    if (t < 48) {
        float g = cab[t];
        for (int c = 0; c < 48; c++) g += sm[c] * caw[c * 48 + t];
        gate[n * 48 + t] = 1.f / (1.f + expf(-g));
    }
}

// ---------------------------------------------------------------------------
// separable antialiased 12^3 -> 4^3 resize (bf16 x1 input)
// ---------------------------------------------------------------------------
__global__ __launch_bounds__(256) void rs1_kernel(const short* __restrict__ x1b,
                                                  const float* __restrict__ locations,
                                                  const float* __restrict__ gate,
                                                  float* __restrict__ t1) {
    const int idx = blockIdx.x * 256 + threadIdx.x;
    int ch = idx % 48;
    int r = idx / 48;
    int c4 = r & 3; r >>= 2;
    int j = r % 12; r /= 12;
    int i = r % 12;
    int n = r / 12;
    const int lz = (int)(locations[n * 3 + 0] * 0.25f) - 6;
    const int ly = (int)(locations[n * 3 + 1] * 0.25f) - 6;
    const int lx = (int)(locations[n * 3 + 2] * 0.25f) - 6;
    const int z = lz + i, y = ly + j;
    float acc = 0.f;
    if ((unsigned)z < 32u && (unsigned)y < 96u) {
        const short* row = x1b + (((long)z * 96 + y) * 96) * 48 + ch;
#pragma unroll
        for (int k = 0; k < 12; k++) {
            const int x = lx + k;
            if ((unsigned)x < 96u) acc += W12c[c4][k] * bf2f(row[(long)x * 48]);
        }
    }
    t1[idx] = acc * gate[n * 48 + ch];
}

__global__ __launch_bounds__(256) void rs2_kernel(const float* __restrict__ t1,
                                                  float* __restrict__ t2) {
    const int idx = blockIdx.x * 256 + threadIdx.x;
    int ch = idx % 48;
    int r = idx / 48;
    int c = r & 3; r >>= 2;
    int b = r & 3; r >>= 2;
    int i = r % 12;
    int n = r / 12;
    float acc = 0.f;
#pragma unroll
    for (int j = 0; j < 12; j++)
        acc += W12c[b][j] * t1[(((long)((n * 12 + i) * 12 + j) * 4 + c)) * 48 + ch];
    t2[idx] = acc;
}

__global__ __launch_bounds__(256) void rs3_kernel(const float* __restrict__ t2,
                                                  float* __restrict__ rs) {
    const int idx = blockIdx.x * 256 + threadIdx.x;
    int ch = idx % 48;
    int r = idx / 48;
    int c = r & 3; r >>= 2;
    int b = r & 3; r >>= 2;
    int a = r & 3;
    int n = r >> 2;
    float acc = 0.f;
#pragma unroll
    for (int i = 0; i < 12; i++)
        acc += W12c[a][i] * t2[(((long)((n * 12 + i) * 4 + b) * 4 + c)) * 48 + ch];
    rs[idx] = acc;
}

// ---------------------------------------------------------------------------
// small dense layers (known good)
// ---------------------------------------------------------------------------
template <int K, bool GEL>
__global__ __launch_bounds__(256) void mlp_kernel(const float* __restrict__ A,
                                                  const float* __restrict__ W,
                                                  const float* __restrict__ bias,
                                                  float* __restrict__ C, int N) {
    const int n = threadIdx.x & 63;
    const int j = blockIdx.x * 4 + (threadIdx.x >> 6);
    float acc = bias[j];
    const float* a = A + (long)n * K;
    const float* wp = W + j;
    for (int k = 0; k < K; k++) acc += a[k] * wp[(long)k * N];
    if (GEL) acc = gelu_f(acc);
    C[(long)n * N + j] = acc;
}

// LayerNorm over 1024 (known good); writes patch_sigs (output 0)
__global__ __launch_bounds__(256) void ln_kernel(const float* __restrict__ s,
                                                 const float* __restrict__ sc,
                                                 const float* __restrict__ bi,
                                                 float* __restrict__ out) {
    __shared__ float red[256];
    const int n = blockIdx.x, tid = threadIdx.x;
    float4 v = ((const float4*)(s + (long)n * 1024))[tid];
    red[tid] = v.x + v.y + v.z + v.w;
    __syncthreads();
    for (int off = 128; off > 0; off >>= 1) {
        if (tid < off) red[tid] += red[tid + off];
        __syncthreads();
    }
    const float mu = red[0] * (1.f / 1024.f);
    __syncthreads();
    const float d0 = v.x - mu, d1 = v.y - mu, d2 = v.z - mu, d3 = v.w - mu;
    red[tid] = d0 * d0 + d1 * d1 + d2 * d2 + d3 * d3;
    __syncthreads();
    for (int off = 128; off > 0; off >>= 1) {
        if (tid < off) red[tid] += red[tid + off];
        __syncthreads();
    }
    const float rstd = rsqrtf(red[0] * (1.f / 1024.f) + 1e-6f);
    const int base = n * 1024 + tid * 4;
    out[base + 0] = d0 * rstd * sc[tid * 4 + 0] + bi[tid * 4 + 0];
    out[base + 1] = d1 * rstd * sc[tid * 4 + 1] + bi[tid * 4 + 1];
    out[base + 2] = d2 * rstd * sc[tid * 4 + 2] + bi[tid * 4 + 2];
    out[base + 3] = d3 * rstd * sc[tid * 4 + 3] + bi[tid * 4 + 3];
}

// ---------------------------------------------------------------------------
// fused pos-enc resize + proj + relu + conv_transpose (bf16 x1 input)
// ---------------------------------------------------------------------------
__global__ __launch_bounds__(256) void deconv_kernel(const short* __restrict__ x1b,
                                                     const float* __restrict__ locations,
                                                     const float* __restrict__ gate,
                                                     const float* __restrict__ p3,
                                                     const float* __restrict__ projw,
                                                     const float* __restrict__ ctw,
                                                     const float* __restrict__ ctb,
                                                     float* __restrict__ l48) {
    __shared__ float s_ctw[384], s_proj[192], s_gate[48];
    const int n = blockIdx.y, tid = threadIdx.x;
    for (int i = tid; i < 384; i += 256) s_ctw[i] = ctw[i];
    if (tid < 192) s_proj[tid] = projw[tid];
    if (tid < 48) s_gate[tid] = gate[n * 48 + tid];
    __syncthreads();
    const int vox = blockIdx.x * 256 + tid;
    const int q = vox % 24, pp = (vox / 24) % 24, m = vox / 576;
    const int lz = (int)(locations[n * 3 + 0] * 0.25f) - 12;
    const int ly = (int)(locations[n * 3 + 1] * 0.25f) - 12;
    const int lx = (int)(locations[n * 3 + 2] * 0.25f) - 12;
    const int z = lz + m, y = ly + pp, x = lx + q;
    float pf[48];
    const bool valid = (unsigned)z < 32u && (unsigned)y < 96u && (unsigned)x < 96u;
    if (valid) {
        const short8_t* src = (const short8_t*)(x1b + (((long)z * 96 + y) * 96 + x) * 48);
#pragma unroll
        for (int t8 = 0; t8 < 6; t8++) {
            const short8_t v = src[t8];
#pragma unroll
            for (int e = 0; e < 8; e++) pf[t8 * 8 + e] = bf2f(v[e]) * s_gate[t8 * 8 + e];
        }
    } else {
#pragma unroll
        for (int c = 0; c < 48; c++) pf[c] = 0.f;
    }
    int jz[2], jy[2], jx[2];
    float wz[2], wy[2], wx[2];
    const float r3 = 1.f / 3.f;
    up_w(m, r3, 7, jz[0], jz[1], wz[0], wz[1]);
    up_w(pp, r3, 7, jy[0], jy[1], wy[0], wy[1]);
    up_w(q, r3, 7, jx[0], jx[1], wx[0], wx[1]);
    const float4* prow = (const float4*)(p3 + (long)n * 2048);
    float prx = 0.f, pry = 0.f, prz = 0.f, prw = 0.f;
#pragma unroll
    for (int a = 0; a < 2; a++)
#pragma unroll
        for (int b = 0; b < 2; b++)
#pragma unroll
            for (int c = 0; c < 2; c++) {
                const float wgt = wz[a] * wy[b] * wx[c];
                float4 v = prow[(jz[a] * 8 + jy[b]) * 8 + jx[c]];
                prx += wgt * v.x;
                pry += wgt * v.y;
                prz += wgt * v.z;
                prw += wgt * v.w;
            }
#pragma unroll
    for (int c = 0; c < 48; c++) {
        float v = pf[c] + prx * s_proj[c] + pry * s_proj[48 + c] + prz * s_proj[96 + c] +
                  prw * s_proj[144 + c];
        pf[c] = fmaxf(v, 0.f);
    }
    const float bias = ctb[0];
#pragma unroll
    for (int a = 0; a < 2; a++)
#pragma unroll
        for (int b = 0; b < 2; b++)
#pragma unroll
            for (int c = 0; c < 2; c++) {
                const float* wrow = s_ctw + (((1 - a) * 2 + (1 - b)) * 2 + (1 - c)) * 48;
                float acc = bias;
#pragma unroll
                for (int ch = 0; ch < 48; ch++) acc += pf[ch] * wrow[ch];
                l48[(((long)n * 48 + 2 * m + a) * 48 + 2 * pp + b) * 48 + 2 * q + c] = acc;
            }
}

// final linear x2 upsample 48^3 -> 96^3 (known good)
__global__ __launch_bounds__(256) void resize96_kernel(const float* __restrict__ l48,
                                                       float* __restrict__ out) {
    const int n = blockIdx.y;
    const int vox = blockIdx.x * 256 + threadIdx.x;
    const int kx = vox % 96, jy = (vox / 96) % 96, iz = vox / 9216;
    int a0, a1, b0, b1, c0, c1;
    float wa0, wa1, wb0, wb1, wc0, wc1;
    up_w(iz, 0.5f, 47, a0, a1, wa0, wa1);
    up_w(jy, 0.5f, 47, b0, b1, wb0, wb1);
    up_w(kx, 0.5f, 47, c0, c1, wc0, wc1);
    const float* base = l48 + (long)n * 110592;
    const float v =
        wa0 * (wb0 * (wc0 * base[(a0 * 48 + b0) * 48 + c0] + wc1 * base[(a0 * 48 + b0) * 48 + c1]) +
               wb1 * (wc0 * base[(a0 * 48 + b1) * 48 + c0] + wc1 * base[(a0 * 48 + b1) * 48 + c1])) +
        wa1 * (wb0 * (wc0 * base[(a1 * 48 + b0) * 48 + c0] + wc1 * base[(a1 * 48 + b0) * 48 + c1]) +
               wb1 * (wc0 * base[(a1 * 48 + b1) * 48 + c0] + wc1 * base[(a1 * 48 + b1) * 48 + c1]));
    out[(long)n * 884736 + vox] = v;
}

__global__ void tail_kernel(const float* __restrict__ locations, float* __restrict__ out) {
    const int n = threadIdx.x;
    if (n < NLOC) {
        const float l0 = locations[n * 3 + 0] * 0.25f;
        const float l1 = locations[n * 3 + 1] * 0.25f;
        const float l2 = locations[n * 3 + 2] * 0.25f;
        const int z = (int)l0 - 12, y = (int)l1 - 12, x = (int)l2 - 12;
        const bool mask = (l2 >= 0.f);
        out[n] = mask ? (float)(z * 4) : -1.f;
        out[64 + n] = mask ? (float)(y * 4) : -1.f;
        out[128 + n] = mask ? (float)(x * 4) : -1.f;
        out[192 + n] = mask ? 1.f : 0.f;
    }
}

// ---------------------------------------------------------------------------
// workspace layout (peak 113.2 MB envelope). x1b is bf16 (half region).
// ---------------------------------------------------------------------------
static const size_t OFF_X0 = 0;                 // bf16 x0b: 7,077,888 floats
static const size_t OFF_X1 = 14155776;          // bf16 x1b: 3,538,944 floats
static const size_t OFF_WF0 = 14155776;         // parked; dead before conv1 writes x1b
static const size_t OFF_GATE = 4096;            // dead-x0b reuse
static const size_t OFF_T1 = 8192;
static const size_t OFF_T2 = 1777664;
static const size_t OFF_RS = 2367488;
static const size_t OFF_S = 2564096;
static const size_t OFF_P1 = 2629632;
static const size_t OFF_P2 = 2695168;
static const size_t OFF_P3 = 2760704;
static const size_t OFF_L48 = 2891776;          // ends 9,969,664
static const size_t OFF_PART = 10000000;        // 73,728 -> 10,073,728 < 14,155,776

// d_out offsets (floats): logits at [65536, 56688640); wf1 parked at start.
static const size_t OUT_WF1 = 65536;            // 41,472 floats (ends 107,008)

extern "C" void kernel_launch(void* const* d_in, const int* in_sizes, int n_in,
                              void* d_out, int out_size, void* d_ws, size_t ws_size,
                              hipStream_t stream) {
    const float* feature = (const float*)d_in[0];
    const float* locations = (const float*)d_in[1];
    const float* w0 = (const float*)d_in[2];
    const float* b0 = (const float*)d_in[3];
    const float* w1 = (const float*)d_in[4];
    const float* b1 = (const float*)d_in[5];
    const float* caw = (const float*)d_in[6];
    const float* cab = (const float*)d_in[7];
    const float* sigw = (const float*)d_in[8];
    const float* sigb = (const float*)d_in[9];
    const float* lnsc = (const float*)d_in[10];
    const float* lnbi = (const float*)d_in[11];
    const float* pe1w = (const float*)d_in[12];
    const float* pe1b = (const float*)d_in[13];
    const float* pe2w = (const float*)d_in[14];
    const float* pe2b = (const float*)d_in[15];
    const float* pe3w = (const float*)d_in[16];
    const float* pe3b = (const float*)d_in[17];
    const float* projw = (const float*)d_in[18];
    const float* ctw = (const float*)d_in[19];
    const float* ctb = (const float*)d_in[20];
    float* ws = (float*)d_ws;
    float* out = (float*)d_out;

    short* x0b = (short*)(ws + OFF_X0);
    short* x1b = (short*)(ws + OFF_X1);
    short* wf0 = (short*)(ws + OFF_WF0);
    short* wf1 = (short*)(out + OUT_WF1);

    // weight packing
    prep_w0_kernel<<<162, 256, 0, stream>>>(w0, wf0);
    prep_w1_kernel<<<41, 256, 0, stream>>>(w1, wf1);

    // MFMA convs, full bf16 chain
    conv0_mfma<<<1152, 256, 0, stream>>>(feature, wf0, b0, x0b);
    conv1_mfma_b<<<1152, 256, 0, stream>>>(x0b, wf1, b1, x1b);

    // gate — per-z-slice partials
    mean_part_kernel<<<dim3(64, 24), 256, 0, stream>>>(x1b, locations, ws + OFF_PART);
    gate_kernel<<<64, 64, 0, stream>>>(ws + OFF_PART, caw, cab, ws + OFF_GATE);

    // inner 12^3 -> 4^3 separable resize
    rs1_kernel<<<6912, 256, 0, stream>>>(x1b, locations, ws + OFF_GATE, ws + OFF_T1);
    rs2_kernel<<<2304, 256, 0, stream>>>(ws + OFF_T1, ws + OFF_T2);
    rs3_kernel<<<768, 256, 0, stream>>>(ws + OFF_T2, ws + OFF_RS);

    // sig GEMM + LayerNorm -> patch_sigs
    mlp_kernel<3072, false><<<256, 256, 0, stream>>>(ws + OFF_RS, sigw, sigb, ws + OFF_S, 1024);
    ln_kernel<<<64, 256, 0, stream>>>(ws + OFF_S, lnsc, lnbi, out);

    // pos-enc MLP
    mlp_kernel<1024, true><<<256, 256, 0, stream>>>(out, pe1w, pe1b, ws + OFF_P1, 1024);
    mlp_kernel<1024, true><<<256, 256, 0, stream>>>(ws + OFF_P1, pe2w, pe2b, ws + OFF_P2, 1024);
    mlp_kernel<1024, false><<<512, 256, 0, stream>>>(ws + OFF_P2, pe3w, pe3b, ws + OFF_P3, 2048);

    // fused pos-enc resize + proj + relu + conv_transpose
    deconv_kernel<<<dim3(54, 64), 256, 0, stream>>>(x1b, locations, ws + OFF_GATE, ws + OFF_P3,
                                                    projw, ctw, ctb, ws + OFF_L48);

    // final x2 upsample -> logits (overwrites wf1 scratch)
    resize96_kernel<<<dim3(3456, 64), 256, 0, stream>>>(ws + OFF_L48, out + 65536);

    // plocs + mask
    tail_kernel<<<1, 64, 0, stream>>>(locations, out + 56688640);
}

// Round 17
// 1221.034 us; speedup vs baseline: 1.3838x; 1.0116x over previous
//
#include <hip/hip_runtime.h>
#include <hip/hip_bf16.h>
#include <math.h>

// ---------------------------------------------------------------------------
// Base = round-16 passing build (1.235 ms). Delta: conv0 B-fragment access.
//  - wf0 re-laid out kk-major: [kk][tap][nt][lane][e]. Per K-slab the B-data
//    (81 KB) now streams sequentially instead of 27 touches at 24 KB stride
//    over 648 KB (L2-latency-bound in a non-unrolled loop).
//  - #pragma unroll 3 on the tap loop for load lookahead.
// Arithmetic identical -> absmax unchanged. Everything else = r16.
// ---------------------------------------------------------------------------

#define NLOC 64

typedef __attribute__((ext_vector_type(8))) short short8_t;
typedef __attribute__((ext_vector_type(4))) float f32x4;

__device__ __forceinline__ float gelu_f(float x) {
    return 0.5f * x * (1.0f + tanhf(0.7978845608028654f * (x + 0.044715f * x * x * x)));
}

__device__ __forceinline__ short f2bf(float x) {
    union { __hip_bfloat16 h; short s; } u;
    u.h = __float2bfloat16(x);
    return u.s;
}

__device__ __forceinline__ float bf2f(short s) {
    union { unsigned u; float f; } u;
    u.u = ((unsigned)(unsigned short)s) << 16;
    return u.f;
}

// antialiased linear 12 -> 4 weight matrix (jax.image.resize, scale=1/3)
__constant__ float W12c[4][12] = {
    {0.25f, 0.375f, 0.25f, 0.125f, 0.f, 0.f, 0.f, 0.f, 0.f, 0.f, 0.f, 0.f},
    {0.f, 0.f, 1.f/9.f, 2.f/9.f, 1.f/3.f, 2.f/9.f, 1.f/9.f, 0.f, 0.f, 0.f, 0.f, 0.f},
    {0.f, 0.f, 0.f, 0.f, 0.f, 1.f/9.f, 2.f/9.f, 1.f/3.f, 2.f/9.f, 1.f/9.f, 0.f, 0.f},
    {0.f, 0.f, 0.f, 0.f, 0.f, 0.f, 0.f, 0.f, 0.125f, 0.25f, 0.375f, 0.25f}};

__device__ __forceinline__ void up_w(int i, float ratio, int inmax,
                                     int& j0, int& j1, float& w0, float& w1) {
    float c = ((float)i + 0.5f) * ratio - 0.5f;
    float fj = floorf(c);
    float f = c - fj;
    int jj = (int)fj;
    j0 = min(max(jj, 0), inmax);
    j1 = min(max(jj + 1, 0), inmax);
    w0 = 1.f - f;
    w1 = f;
}

// ---------------------------------------------------------------------------
// weight fragment packing.
// wf0 KK-MAJOR this round: [kk(8)][tap(27)][nt(3)][lane][e]
//   ci = kk*32 + 8g + e, co = nt*16 + (lane&15)
// ---------------------------------------------------------------------------
__global__ void prep_w0_kernel(const float* __restrict__ w0, short* __restrict__ wf) {
    const int tid = blockIdx.x * 256 + threadIdx.x;
    if (tid >= 8 * 27 * 3 * 64) return;
    const int lane = tid & 63;
    const int t2 = tid >> 6;
    const int nt = t2 % 3;
    const int t3 = t2 / 3;
    const int tap = t3 % 27, kk = t3 / 27;
    const int g = lane >> 4, rr = lane & 15;
    const int co = nt * 16 + rr;
    short8_t frag;
#pragma unroll
    for (int e = 0; e < 8; e++) {
        const int ci = kk * 32 + g * 8 + e;
        frag[e] = f2bf(w0[((long)(tap * 256 + ci)) * 48 + co]);
    }
    ((short8_t*)wf)[tid] = frag;
}

// wf1[tap][kk(2)][nt(3)][lane][e] (unchanged; tap-outer loop streams it)
__global__ void prep_w1_kernel(const float* __restrict__ w1, short* __restrict__ wf) {
    const int tid = blockIdx.x * 256 + threadIdx.x;
    if (tid >= 27 * 2 * 3 * 64) return;
    const int lane = tid & 63;
    const int t2 = tid >> 6;
    const int nt = t2 % 3;
    const int t3 = t2 / 3;
    const int kk = t3 & 1, tap = t3 >> 1;
    const int g = lane >> 4, rr = lane & 15;
    const int co = nt * 16 + rr;
    short8_t frag;
#pragma unroll
    for (int e = 0; e < 8; e++) {
        const int ci = kk * 32 + g * 8 + e;
        frag[e] = (ci < 48) ? f2bf(w1[((long)(tap * 48 + ci)) * 48 + co]) : (short)0;
    }
    ((short8_t*)wf)[tid] = frag;
}

// ---------------------------------------------------------------------------
// conv0: fused cast + LDS halo staging + MFMA; bf16 output.
// B reads stream sequentially within each slab (kk-major wf0) + unroll 3.
// ---------------------------------------------------------------------------
#define HV 600
#define HSTR 40  // shorts per halo row (32 + 8 pad)

__global__ __launch_bounds__(256) void conv0_mfma(const float* __restrict__ feat,
                                                  const short* __restrict__ wf,
                                                  const float* __restrict__ bias,
                                                  short* __restrict__ x0b) {
    __shared__ short slds[HV * HSTR];
    const int tid = threadIdx.x;
    const int lane = tid & 63, wid = tid >> 6;
    const int g = lane >> 4, r = lane & 15;
    const int bz = blockIdx.x / 144, by = (blockIdx.x / 12) % 12, bx = blockIdx.x % 12;
    const int z0 = bz * 4, y0 = by * 8, x0c = bx * 8;
    int h0[4];
#pragma unroll
    for (int mt = 0; mt < 4; mt++) {
        const int t = wid * 64 + mt * 16 + r;
        h0[mt] = ((t >> 6) * 10 + ((t >> 3) & 7)) * 10 + (t & 7);
    }
    f32x4 acc[4][3];
#pragma unroll
    for (int mt = 0; mt < 4; mt++)
#pragma unroll
        for (int nt = 0; nt < 3; nt++) acc[mt][nt] = (f32x4){0.f, 0.f, 0.f, 0.f};
    const short8_t zfrag = {0, 0, 0, 0, 0, 0, 0, 0};
    const short8_t* wf8 = (const short8_t*)wf;

    for (int kk = 0; kk < 8; kk++) {
        __syncthreads();
        for (int h = tid; h < HV; h += 256) {
            const int hx = h % 10, hy = (h / 10) % 10, hz = h / 100;
            const int zz = z0 + hz - 1, yy = y0 + hy - 1, xx = x0c + hx - 1;
            short8_t s8[4];
            if ((unsigned)zz < 32u && (unsigned)yy < 96u && (unsigned)xx < 96u) {
                const float4* src =
                    (const float4*)(feat + (((((long)zz * 96 + yy) * 96 + xx)) << 8) + kk * 32);
#pragma unroll
                for (int q = 0; q < 4; q++) {
                    const float4 a = src[2 * q], b = src[2 * q + 1];
                    s8[q][0] = f2bf(a.x); s8[q][1] = f2bf(a.y);
                    s8[q][2] = f2bf(a.z); s8[q][3] = f2bf(a.w);
                    s8[q][4] = f2bf(b.x); s8[q][5] = f2bf(b.y);
                    s8[q][6] = f2bf(b.z); s8[q][7] = f2bf(b.w);
                }
            } else {
#pragma unroll
                for (int q = 0; q < 4; q++) s8[q] = zfrag;
            }
            short8_t* dst = (short8_t*)(slds + h * HSTR);
#pragma unroll
            for (int q = 0; q < 4; q++) dst[q] = s8[q];
        }
        __syncthreads();
        // B-data for this slab: wf8[kk*81*64 ...], streamed sequentially
        const short8_t* bslab = wf8 + (size_t)kk * 27 * 3 * 64 + lane;
#pragma unroll 3
        for (int tap = 0; tap < 27; tap++) {
            const int dh = (tap / 9) * 100 + ((tap / 3) % 3) * 10 + (tap % 3);
            short8_t bfr[3];
#pragma unroll
            for (int nt = 0; nt < 3; nt++)
                bfr[nt] = bslab[(tap * 3 + nt) * 64];
            short8_t afr[4];
#pragma unroll
            for (int mt = 0; mt < 4; mt++)
                afr[mt] = *(const short8_t*)(slds + (h0[mt] + dh) * HSTR + g * 8);
#pragma unroll
            for (int mt = 0; mt < 4; mt++)
#pragma unroll
                for (int nt = 0; nt < 3; nt++)
                    acc[mt][nt] = __builtin_amdgcn_mfma_f32_16x16x32_bf16(afr[mt], bfr[nt],
                                                                          acc[mt][nt], 0, 0, 0);
        }
    }
    // D mapping: col = lane&15, row = g*4 + reg. bf16 output.
#pragma unroll
    for (int nt = 0; nt < 3; nt++) {
        const int co = nt * 16 + r;
        const float bv = bias[co];
#pragma unroll
        for (int mt = 0; mt < 4; mt++) {
#pragma unroll
            for (int rg = 0; rg < 4; rg++) {
                const int t = wid * 64 + mt * 16 + g * 4 + rg;
                const int z = z0 + (t >> 6), y = y0 + ((t >> 3) & 7), x = x0c + (t & 7);
                const long gi = ((long)z * 96 + y) * 96 + x;
                x0b[gi * 48 + co] = f2bf(gelu_f(acc[mt][nt][rg] + bv));
            }
        }
    }
}

// ---------------------------------------------------------------------------
// conv1: bf16 in, single full-48ch halo staging, bf16 out (validated r14)
// ---------------------------------------------------------------------------
#define C1ROW 48

__global__ __launch_bounds__(256, 1) void conv1_mfma_b(const short* __restrict__ x0b,
                                                       const short* __restrict__ wf,
                                                       const float* __restrict__ bias,
                                                       short* __restrict__ x1b) {
    __shared__ short slds[HV * C1ROW];
    const int tid = threadIdx.x;
    const int lane = tid & 63, wid = tid >> 6;
    const int g = lane >> 4, r = lane & 15;
    const int bz = blockIdx.x / 144, by = (blockIdx.x / 12) % 12, bx = blockIdx.x % 12;
    const int z0 = bz * 4, y0 = by * 8, x0c = bx * 8;
    int h0[4];
#pragma unroll
    for (int mt = 0; mt < 4; mt++) {
        const int t = wid * 64 + mt * 16 + r;
        h0[mt] = ((t >> 6) * 10 + ((t >> 3) & 7)) * 10 + (t & 7);
    }
    f32x4 acc[4][3];
#pragma unroll
    for (int mt = 0; mt < 4; mt++)
#pragma unroll
        for (int nt = 0; nt < 3; nt++) acc[mt][nt] = (f32x4){0.f, 0.f, 0.f, 0.f};
    const short8_t zfrag = {0, 0, 0, 0, 0, 0, 0, 0};
    const short8_t* wf8 = (const short8_t*)wf;

    for (int h = tid; h < HV; h += 256) {
        const int hx = h % 10, hy = (h / 10) % 10, hz = h / 100;
        const int zz = z0 + hz - 1, yy = y0 + hy - 1, xx = x0c + hx - 1;
        short8_t s8[6];
        if ((unsigned)zz < 32u && (unsigned)yy < 96u && (unsigned)xx < 96u) {
            const short8_t* src = (const short8_t*)(x0b + (((long)zz * 96 + yy) * 96 + xx) * 48);
#pragma unroll
            for (int q = 0; q < 6; q++) s8[q] = src[q];
        } else {
#pragma unroll
            for (int q = 0; q < 6; q++) s8[q] = zfrag;
        }
        short8_t* dst = (short8_t*)(slds + h * C1ROW);
#pragma unroll
        for (int q = 0; q < 6; q++) dst[q] = s8[q];
    }
    __syncthreads();

    for (int tap = 0; tap < 27; tap++) {
        const int dh = (tap / 9) * 100 + ((tap / 3) % 3) * 10 + (tap % 3);
#pragma unroll
        for (int kk = 0; kk < 2; kk++) {
            short8_t bfr[3];
#pragma unroll
            for (int nt = 0; nt < 3; nt++)
                bfr[nt] = wf8[(size_t)tap * 384 + kk * 192 + nt * 64 + lane];
            short8_t afr[4];
#pragma unroll
            for (int mt = 0; mt < 4; mt++) {
                afr[mt] = zfrag;
                if (!(kk == 1 && g >= 2))  // ci = kk*32+8g < 48
                    afr[mt] =
                        *(const short8_t*)(slds + (h0[mt] + dh) * C1ROW + kk * 32 + g * 8);
            }
#pragma unroll
            for (int mt = 0; mt < 4; mt++)
#pragma unroll
                for (int nt = 0; nt < 3; nt++)
                    acc[mt][nt] = __builtin_amdgcn_mfma_f32_16x16x32_bf16(afr[mt], bfr[nt],
                                                                          acc[mt][nt], 0, 0, 0);
        }
    }
#pragma unroll
    for (int nt = 0; nt < 3; nt++) {
        const int co = nt * 16 + r;
        const float bv = bias[co];
#pragma unroll
        for (int mt = 0; mt < 4; mt++) {
#pragma unroll
            for (int rg = 0; rg < 4; rg++) {
                const int t = wid * 64 + mt * 16 + g * 4 + rg;
                const int z = z0 + (t >> 6), y = y0 + ((t >> 3) & 7), x = x0c + (t & 7);
                const long gi = ((long)z * 96 + y) * 96 + x;
                x1b[gi * 48 + co] = f2bf(acc[mt][nt][rg] + bv);
            }
        }
    }
}

// ---------------------------------------------------------------------------
// per-patch channel partial sums per z-slice (bf16 x1); part[n][i][48]
// ---------------------------------------------------------------------------
__global__ __launch_bounds__(256) void mean_part_kernel(const short* __restrict__ x1b,
                                                        const float* __restrict__ locations,
                                                        float* __restrict__ part) {
    __shared__ float red[256];
    const int n = blockIdx.x, i = blockIdx.y;
    const int tid = threadIdx.x;
    const int ch = tid & 63, grp = tid >> 6;
    const int lz = (int)(locations[n * 3 + 0] * 0.25f) - 12;
    const int ly = (int)(locations[n * 3 + 1] * 0.25f) - 12;
    const int lx = (int)(locations[n * 3 + 2] * 0.25f) - 12;
    float acc = 0.f;
    const int z = lz + i;
    if (ch < 48 && (unsigned)z < 32u) {
        for (int p = grp; p < 576; p += 4) {
            const int j = p / 24, k = p % 24;
            const int y = ly + j, x = lx + k;
            if ((unsigned)y < 96u && (unsigned)x < 96u)
                acc += bf2f(x1b[(((long)z * 96 + y) * 96 + x) * 48 + ch]);
        }
    }
    red[tid] = acc;
    __syncthreads();
    if (tid < 48)
        part[(n * 24 + i) * 48 + tid] = red[tid] + red[tid + 64] + red[tid + 128] + red[tid + 192];
}

__global__ void gate_kernel(const float* __restrict__ part, const float* __restrict__ caw,
                            const float* __restrict__ cab, float* __restrict__ gate) {
    __shared__ float sm[48];
    const int n = blockIdx.x, t = threadIdx.x;
    if (t < 48) {
        float a = 0.f;
        for (int i = 0; i < 24; i++) a += part[(n * 24 + i) * 48 + t];
        sm[t] = a * (1.f / 13824.f);
    }
    __syncthreads();
    if (t < 48) {
        float g = cab[t];
        for (int c = 0; c < 48; c++) g += sm[c] * caw[c * 48 + t];
        gate[n * 48 + t] = 1.f / (1.f + expf(-g));
    }
}

// ---------------------------------------------------------------------------
// separable antialiased 12^3 -> 4^3 resize (bf16 x1 input)
// ---------------------------------------------------------------------------
__global__ __launch_bounds__(256) void rs1_kernel(const short* __restrict__ x1b,
                                                  const float* __restrict__ locations,
                                                  const float* __restrict__ gate,
                                                  float* __restrict__ t1) {
    const int idx = blockIdx.x * 256 + threadIdx.x;
    int ch = idx % 48;
    int r = idx / 48;
    int c4 = r & 3; r >>= 2;
    int j = r % 12; r /= 12;
    int i = r % 12;
    int n = r / 12;
    const int lz = (int)(locations[n * 3 + 0] * 0.25f) - 6;
    const int ly = (int)(locations[n * 3 + 1] * 0.25f) - 6;
    const int lx = (int)(locations[n * 3 + 2] * 0.25f) - 6;
    const int z = lz + i, y = ly + j;
    float acc = 0.f;
    if ((unsigned)z < 32u && (unsigned)y < 96u) {
        const short* row = x1b + (((long)z * 96 + y) * 96) * 48 + ch;
#pragma unroll
        for (int k = 0; k < 12; k++) {
            const int x = lx + k;
            if ((unsigned)x < 96u) acc += W12c[c4][k] * bf2f(row[(long)x * 48]);
        }
    }
    t1[idx] = acc * gate[n * 48 + ch];
}

__global__ __launch_bounds__(256) void rs2_kernel(const float* __restrict__ t1,
                                                  float* __restrict__ t2) {
    const int idx = blockIdx.x * 256 + threadIdx.x;
    int ch = idx % 48;
    int r = idx / 48;
    int c = r & 3; r >>= 2;
    int b = r & 3; r >>= 2;
    int i = r % 12;
    int n = r / 12;
    float acc = 0.f;
#pragma unroll
    for (int j = 0; j < 12; j++)
        acc += W12c[b][j] * t1[(((long)((n * 12 + i) * 12 + j) * 4 + c)) * 48 + ch];
    t2[idx] = acc;
}

__global__ __launch_bounds__(256) void rs3_kernel(const float* __restrict__ t2,
                                                  float* __restrict__ rs) {
    const int idx = blockIdx.x * 256 + threadIdx.x;
    int ch = idx % 48;
    int r = idx / 48;
    int c = r & 3; r >>= 2;
    int b = r & 3; r >>= 2;
    int a = r & 3;
    int n = r >> 2;
    float acc = 0.f;
#pragma unroll
    for (int i = 0; i < 12; i++)
        acc += W12c[a][i] * t2[(((long)((n * 12 + i) * 4 + b) * 4 + c)) * 48 + ch];
    rs[idx] = acc;
}

// ---------------------------------------------------------------------------
// small dense layers (known good)
// ---------------------------------------------------------------------------
template <int K, bool GEL>
__global__ __launch_bounds__(256) void mlp_kernel(const float* __restrict__ A,
                                                  const float* __restrict__ W,
                                                  const float* __restrict__ bias,
                                                  float* __restrict__ C, int N) {
    const int n = threadIdx.x & 63;
    const int j = blockIdx.x * 4 + (threadIdx.x >> 6);
    float acc = bias[j];
    const float* a = A + (long)n * K;
    const float* wp = W + j;
    for (int k = 0; k < K; k++) acc += a[k] * wp[(long)k * N];
    if (GEL) acc = gelu_f(acc);
    C[(long)n * N + j] = acc;
}

// LayerNorm over 1024 (known good); writes patch_sigs (output 0)
__global__ __launch_bounds__(256) void ln_kernel(const float* __restrict__ s,
                                                 const float* __restrict__ sc,
                                                 const float* __restrict__ bi,
                                                 float* __restrict__ out) {
    __shared__ float red[256];
    const int n = blockIdx.x, tid = threadIdx.x;
    float4 v = ((const float4*)(s + (long)n * 1024))[tid];
    red[tid] = v.x + v.y + v.z + v.w;
    __syncthreads();
    for (int off = 128; off > 0; off >>= 1) {
        if (tid < off) red[tid] += red[tid + off];
        __syncthreads();
    }
    const float mu = red[0] * (1.f / 1024.f);
    __syncthreads();
    const float d0 = v.x - mu, d1 = v.y - mu, d2 = v.z - mu, d3 = v.w - mu;
    red[tid] = d0 * d0 + d1 * d1 + d2 * d2 + d3 * d3;
    __syncthreads();
    for (int off = 128; off > 0; off >>= 1) {
        if (tid < off) red[tid] += red[tid + off];
        __syncthreads();
    }
    const float rstd = rsqrtf(red[0] * (1.f / 1024.f) + 1e-6f);
    const int base = n * 1024 + tid * 4;
    out[base + 0] = d0 * rstd * sc[tid * 4 + 0] + bi[tid * 4 + 0];
    out[base + 1] = d1 * rstd * sc[tid * 4 + 1] + bi[tid * 4 + 1];
    out[base + 2] = d2 * rstd * sc[tid * 4 + 2] + bi[tid * 4 + 2];
    out[base + 3] = d3 * rstd * sc[tid * 4 + 3] + bi[tid * 4 + 3];
}

// ---------------------------------------------------------------------------
// fused pos-enc resize + proj + relu + conv_transpose (bf16 x1 input)
// ---------------------------------------------------------------------------
__global__ __launch_bounds__(256) void deconv_kernel(const short* __restrict__ x1b,
                                                     const float* __restrict__ locations,
                                                     const float* __restrict__ gate,
                                                     const float* __restrict__ p3,
                                                     const float* __restrict__ projw,
                                                     const float* __restrict__ ctw,
                                                     const float* __restrict__ ctb,
                                                     float* __restrict__ l48) {
    __shared__ float s_ctw[384], s_proj[192], s_gate[48];
    const int n = blockIdx.y, tid = threadIdx.x;
    for (int i = tid; i < 384; i += 256) s_ctw[i] = ctw[i];
    if (tid < 192) s_proj[tid] = projw[tid];
    if (tid < 48) s_gate[tid] = gate[n * 48 + tid];
    __syncthreads();
    const int vox = blockIdx.x * 256 + tid;
    const int q = vox % 24, pp = (vox / 24) % 24, m = vox / 576;
    const int lz = (int)(locations[n * 3 + 0] * 0.25f) - 12;
    const int ly = (int)(locations[n * 3 + 1] * 0.25f) - 12;
    const int lx = (int)(locations[n * 3 + 2] * 0.25f) - 12;
    const int z = lz + m, y = ly + pp, x = lx + q;
    float pf[48];
    const bool valid = (unsigned)z < 32u && (unsigned)y < 96u && (unsigned)x < 96u;
    if (valid) {
        const short8_t* src = (const short8_t*)(x1b + (((long)z * 96 + y) * 96 + x) * 48);
#pragma unroll
        for (int t8 = 0; t8 < 6; t8++) {
            const short8_t v = src[t8];
#pragma unroll
            for (int e = 0; e < 8; e++) pf[t8 * 8 + e] = bf2f(v[e]) * s_gate[t8 * 8 + e];
        }
    } else {
#pragma unroll
        for (int c = 0; c < 48; c++) pf[c] = 0.f;
    }
    int jz[2], jy[2], jx[2];
    float wz[2], wy[2], wx[2];
    const float r3 = 1.f / 3.f;
    up_w(m, r3, 7, jz[0], jz[1], wz[0], wz[1]);
    up_w(pp, r3, 7, jy[0], jy[1], wy[0], wy[1]);
    up_w(q, r3, 7, jx[0], jx[1], wx[0], wx[1]);
    const float4* prow = (const float4*)(p3 + (long)n * 2048);
    float prx = 0.f, pry = 0.f, prz = 0.f, prw = 0.f;
#pragma unroll
    for (int a = 0; a < 2; a++)
#pragma unroll
        for (int b = 0; b < 2; b++)
#pragma unroll
            for (int c = 0; c < 2; c++) {
                const float wgt = wz[a] * wy[b] * wx[c];
                float4 v = prow[(jz[a] * 8 + jy[b]) * 8 + jx[c]];
                prx += wgt * v.x;
                pry += wgt * v.y;
                prz += wgt * v.z;
                prw += wgt * v.w;
            }
#pragma unroll
    for (int c = 0; c < 48; c++) {
        float v = pf[c] + prx * s_proj[c] + pry * s_proj[48 + c] + prz * s_proj[96 + c] +
                  prw * s_proj[144 + c];
        pf[c] = fmaxf(v, 0.f);
    }
    const float bias = ctb[0];
#pragma unroll
    for (int a = 0; a < 2; a++)
#pragma unroll
        for (int b = 0; b < 2; b++)
#pragma unroll
            for (int c = 0; c < 2; c++) {
                const float* wrow = s_ctw + (((1 - a) * 2 + (1 - b)) * 2 + (1 - c)) * 48;
                float acc = bias;
#pragma unroll
                for (int ch = 0; ch < 48; ch++) acc += pf[ch] * wrow[ch];
                l48[(((long)n * 48 + 2 * m + a) * 48 + 2 * pp + b) * 48 + 2 * q + c] = acc;
            }
}

// final linear x2 upsample 48^3 -> 96^3 (known good)
__global__ __launch_bounds__(256) void resize96_kernel(const float* __restrict__ l48,
                                                       float* __restrict__ out) {
    const int n = blockIdx.y;
    const int vox = blockIdx.x * 256 + threadIdx.x;
    const int kx = vox % 96, jy = (vox / 96) % 96, iz = vox / 9216;
    int a0, a1, b0, b1, c0, c1;
    float wa0, wa1, wb0, wb1, wc0, wc1;
    up_w(iz, 0.5f, 47, a0, a1, wa0, wa1);
    up_w(jy, 0.5f, 47, b0, b1, wb0, wb1);
    up_w(kx, 0.5f, 47, c0, c1, wc0, wc1);
    const float* base = l48 + (long)n * 110592;
    const float v =
        wa0 * (wb0 * (wc0 * base[(a0 * 48 + b0) * 48 + c0] + wc1 * base[(a0 * 48 + b0) * 48 + c1]) +
               wb1 * (wc0 * base[(a0 * 48 + b1) * 48 + c0] + wc1 * base[(a0 * 48 + b1) * 48 + c1])) +
        wa1 * (wb0 * (wc0 * base[(a1 * 48 + b0) * 48 + c0] + wc1 * base[(a1 * 48 + b0) * 48 + c1]) +
               wb1 * (wc0 * base[(a1 * 48 + b1) * 48 + c0] + wc1 * base[(a1 * 48 + b1) * 48 + c1]));
    out[(long)n * 884736 + vox] = v;
}

__global__ void tail_kernel(const float* __restrict__ locations, float* __restrict__ out) {
    const int n = threadIdx.x;
    if (n < NLOC) {
        const float l0 = locations[n * 3 + 0] * 0.25f;
        const float l1 = locations[n * 3 + 1] * 0.25f;
        const float l2 = locations[n * 3 + 2] * 0.25f;
        const int z = (int)l0 - 12, y = (int)l1 - 12, x = (int)l2 - 12;
        const bool mask = (l2 >= 0.f);
        out[n] = mask ? (float)(z * 4) : -1.f;
        out[64 + n] = mask ? (float)(y * 4) : -1.f;
        out[128 + n] = mask ? (float)(x * 4) : -1.f;
        out[192 + n] = mask ? 1.f : 0.f;
    }
}

// ---------------------------------------------------------------------------
// workspace layout (peak 113.2 MB envelope). x1b is bf16 (half region).
// ---------------------------------------------------------------------------
static const size_t OFF_X0 = 0;                 // bf16 x0b: 7,077,888 floats
static const size_t OFF_X1 = 14155776;          // bf16 x1b: 3,538,944 floats
static const size_t OFF_WF0 = 14155776;         // parked; dead before conv1 writes x1b
static const size_t OFF_GATE = 4096;            // dead-x0b reuse
static const size_t OFF_T1 = 8192;
static const size_t OFF_T2 = 1777664;
static const size_t OFF_RS = 2367488;
static const size_t OFF_S = 2564096;
static const size_t OFF_P1 = 2629632;
static const size_t OFF_P2 = 2695168;
static const size_t OFF_P3 = 2760704;
static const size_t OFF_L48 = 2891776;          // ends 9,969,664
static const size_t OFF_PART = 10000000;        // 73,728 -> 10,073,728 < 14,155,776

// d_out offsets (floats): logits at [65536, 56688640); wf1 parked at start.
static const size_t OUT_WF1 = 65536;            // 41,472 floats (ends 107,008)

extern "C" void kernel_launch(void* const* d_in, const int* in_sizes, int n_in,
                              void* d_out, int out_size, void* d_ws, size_t ws_size,
                              hipStream_t stream) {
    const float* feature = (const float*)d_in[0];
    const float* locations = (const float*)d_in[1];
    const float* w0 = (const float*)d_in[2];
    const float* b0 = (const float*)d_in[3];
    const float* w1 = (const float*)d_in[4];
    const float* b1 = (const float*)d_in[5];
    const float* caw = (const float*)d_in[6];
    const float* cab = (const float*)d_in[7];
    const float* sigw = (const float*)d_in[8];
    const float* sigb = (const float*)d_in[9];
    const float* lnsc = (const float*)d_in[10];
    const float* lnbi = (const float*)d_in[11];
    const float* pe1w = (const float*)d_in[12];
    const float* pe1b = (const float*)d_in[13];
    const float* pe2w = (const float*)d_in[14];
    const float* pe2b = (const float*)d_in[15];
    const float* pe3w = (const float*)d_in[16];
    const float* pe3b = (const float*)d_in[17];
    const float* projw = (const float*)d_in[18];
    const float* ctw = (const float*)d_in[19];
    const float* ctb = (const float*)d_in[20];
    float* ws = (float*)d_ws;
    float* out = (float*)d_out;

    short* x0b = (short*)(ws + OFF_X0);
    short* x1b = (short*)(ws + OFF_X1);
    short* wf0 = (short*)(ws + OFF_WF0);
    short* wf1 = (short*)(out + OUT_WF1);

    // weight packing (wf0 kk-major this round)
    prep_w0_kernel<<<162, 256, 0, stream>>>(w0, wf0);
    prep_w1_kernel<<<41, 256, 0, stream>>>(w1, wf1);

    // MFMA convs, full bf16 chain
    conv0_mfma<<<1152, 256, 0, stream>>>(feature, wf0, b0, x0b);
    conv1_mfma_b<<<1152, 256, 0, stream>>>(x0b, wf1, b1, x1b);

    // gate — per-z-slice partials
    mean_part_kernel<<<dim3(64, 24), 256, 0, stream>>>(x1b, locations, ws + OFF_PART);
    gate_kernel<<<64, 64, 0, stream>>>(ws + OFF_PART, caw, cab, ws + OFF_GATE);

    // inner 12^3 -> 4^3 separable resize
    rs1_kernel<<<6912, 256, 0, stream>>>(x1b, locations, ws + OFF_GATE, ws + OFF_T1);
    rs2_kernel<<<2304, 256, 0, stream>>>(ws + OFF_T1, ws + OFF_T2);
    rs3_kernel<<<768, 256, 0, stream>>>(ws + OFF_T2, ws + OFF_RS);

    // sig GEMM + LayerNorm -> patch_sigs
    mlp_kernel<3072, false><<<256, 256, 0, stream>>>(ws + OFF_RS, sigw, sigb, ws + OFF_S, 1024);
    ln_kernel<<<64, 256, 0, stream>>>(ws + OFF_S, lnsc, lnbi, out);

    // pos-enc MLP
    mlp_kernel<1024, true><<<256, 256, 0, stream>>>(out, pe1w, pe1b, ws + OFF_P1, 1024);
    mlp_kernel<1024, true><<<256, 256, 0, stream>>>(ws + OFF_P1, pe2w, pe2b, ws + OFF_P2, 1024);
    mlp_kernel<1024, false><<<512, 256, 0, stream>>>(ws + OFF_P2, pe3w, pe3b, ws + OFF_P3, 2048);

    // fused pos-enc resize + proj + relu + conv_transpose
    deconv_kernel<<<dim3(54, 64), 256, 0, stream>>>(x1b, locations, ws + OFF_GATE, ws + OFF_P3,
                                                    projw, ctw, ctb, ws + OFF_L48);

    // final x2 upsample -> logits (overwrites wf1 scratch)
    resize96_kernel<<<dim3(3456, 64), 256, 0, stream>>>(ws + OFF_L48, out + 65536);

    // plocs + mask
    tail_kernel<<<1, 64, 0, stream>>>(locations, out + 56688640);
}